// Round 6
// baseline (35.732 us; speedup 1.0000x reference)
//
#include <hip/hip_runtime.h>
#include <math.h>

#define N 2048
#define D 64
#define KP 4
#define PI_F 3.14159265358979f
#define ADOM 1.03f      // poly fit domain [-ADOM, ADOM]
#define NDEG 12         // 12 monomial coefficients (degree 11)

typedef unsigned int uint;
typedef unsigned short ushort;
typedef unsigned long long u64;
typedef __attribute__((ext_vector_type(8))) short bf16x8;
typedef __attribute__((ext_vector_type(4))) float f32x4;
typedef __attribute__((ext_vector_type(4))) uint uint4v;

// Chebyshev T_j monomial coefficients: TCmat[j][k] = coeff of u^k in T_j(u)
__device__ static const float TCmat[12][12] = {
  {   1,   0,    0,    0,    0,     0,    0,     0,     0,     0,    0,    0},
  {   0,   1,    0,    0,    0,     0,    0,     0,     0,     0,    0,    0},
  {  -1,   0,    2,    0,    0,     0,    0,     0,     0,     0,    0,    0},
  {   0,  -3,    0,    4,    0,     0,    0,     0,     0,     0,    0,    0},
  {   1,   0,   -8,    0,    8,     0,    0,     0,     0,     0,    0,    0},
  {   0,   5,    0,  -20,    0,    16,    0,     0,     0,     0,    0,    0},
  {  -1,   0,   18,    0,  -48,     0,   32,     0,     0,     0,    0,    0},
  {   0,  -7,    0,   56,    0,  -112,    0,    64,     0,     0,    0,    0},
  {   1,   0,  -32,    0,  160,     0, -256,     0,   128,     0,    0,    0},
  {   0,   9,    0, -120,    0,   432,    0,  -576,     0,   256,    0,    0},
  {  -1,   0,   50,    0, -400,     0, 1120,     0, -1280,     0,  512,    0},
  {   0, -11,    0,  220,    0, -1232,    0,  2816,     0, -2816,    0, 1024},
};

// float -> bf16 round-to-nearest-even
__device__ __forceinline__ ushort f2bf(float f) {
  uint u = __builtin_bit_cast(uint, f);
  u += 0x7FFFu + ((u >> 16) & 1u);
  return (ushort)(u >> 16);
}

// Mask layout: per row, 8 chunks of 256 cols; each chunk = 4 u64 words.
// Bit l of word j  <->  col = chunk*256 + 4*l + j.

// ---------------- Kernel 1: masks + EA + feat + Fn_bf16 + attr_prob -------
// Block 0 additionally fits the per-component polynomials:
//   f_i(S) = tanh(e_i*exp(S/T_i)),  h_i(S) = f_i(S)*tanh(e_i*exp((1-S)/T_i))
// -> monomial coeffs (deg 11) written to `coefs` [KP][2][12].
__global__ __launch_bounds__(256) void row_kernel(
    const float* __restrict__ attr, const float* __restrict__ edges,
    const float* __restrict__ two_hop, const float* __restrict__ persona,
    const int* __restrict__ timesP, const float* __restrict__ rp,
    const float* __restrict__ Wp, const float* __restrict__ Tp,
    const float* __restrict__ ep, ushort* __restrict__ Fnb,
    u64* __restrict__ ME, u64* __restrict__ MT, float* __restrict__ coefs,
    float* __restrict__ out)
{
  __shared__ float part[4][64];

  int t = threadIdx.x;
  int w = t >> 6, l = t & 63;
  int row = blockIdx.x;

  const float4* erow4 = reinterpret_cast<const float4*>(edges + (size_t)row * N);
  const float4* trow4 = reinterpret_cast<const float4*>(two_hop + (size_t)row * N);

  u64 mw[2][4];
  #pragma unroll
  for (int cc = 0; cc < 2; ++cc) {
    int chunk = 2 * w + cc;
    float4 ev = erow4[chunk * 64 + l];
    float4 tv = trow4[chunk * 64 + l];
    int colb = chunk * 256 + 4 * l;
    float evs[4] = {ev.x, ev.y, ev.z, ev.w};
    float tvs[4] = {tv.x, tv.y, tv.z, tv.w};
    #pragma unroll
    for (int jj = 0; jj < 4; ++jj) {
      bool eb = evs[jj] != 0.0f;
      u64 meb = __ballot(eb);
      u64 mtb = __ballot((eb || tvs[jj] != 0.0f) && (colb + jj != row));
      mw[cc][jj] = meb;
      if (l == jj) {
        ME[(size_t)row * 32 + chunk * 4 + jj] = meb;
        MT[(size_t)row * 32 + chunk * 4 + jj] = mtb;
      }
    }
  }

  // EA gather: lane l = dimension d
  float acc = 0.0f;
  #pragma unroll
  for (int cc = 0; cc < 2; ++cc) {
    #pragma unroll
    for (int jj = 0; jj < 4; ++jj) {
      u64 word = mw[cc][jj];
      int base = (2 * w + cc) * 256 + jj;
      while (word) {
        int b = __builtin_ctzll(word);
        word &= word - 1;
        acc += attr[(size_t)(base + 4 * b) * D + l];
      }
    }
  }
  part[w][l] = acc;
  __syncthreads();
  float ea = part[0][l] + part[1][l] + part[2][l] + part[3][l];
  __syncthreads();   // before part reuse

  // wave w handles persona component i = w
  float a = attr[(size_t)row * D + l];
  float ri = rp[w], Wi = Wp[w];
  float nf = ri * a + ea * Wi * (1.0f - ri);
  float ss = nf * nf;
  #pragma unroll
  for (int off = 32; off; off >>= 1) ss += __shfl_xor(ss, off);
  float inv = rsqrtf(ss);
  Fnb[((size_t)w * N + row) * D + l] = f2bf(nf * inv);

  int times = timesP[0];
  float p = persona[((size_t)times * N + row) * KP + w];
  float sig = 1.0f / (1.0f + __expf(-nf));
  part[w][l] = p * sig;
  __syncthreads();
  if (w == 0) {
    out[(size_t)N * N + (size_t)row * D + l] =
        part[0][l] + part[1][l] + part[2][l] + part[3][l];
  }

  // ---- block 0: polynomial fits (wave w handles component i = w) ----
  if (row == 0) {
    __syncthreads();   // part free for reuse (block-uniform branch)
    float invT = 1.0f / Tp[w];
    float ei = ep[w];
    // node values: lanes 0..31 -> f at node k=l; lanes 32..63 -> h at k=l-32
    int k = l & 31;
    float x = cosf(PI_F * (k + 0.5f) / 32.0f);   // Chebyshev node in [-1,1]
    float s = ADOM * x;
    float fv = tanhf(ei * expf(s * invT));
    float hv = fv * tanhf(ei * expf((1.0f - s) * invT));
    part[w][l] = (l < 32) ? fv : hv;
    __syncthreads();
    // DCT: lanes 0..11 -> cheb coeffs of f; lanes 16..27 -> of h
    int j = l & 15;
    bool doF = (l < 12);
    bool doH = (l >= 16 && l < 28);
    float c = 0.0f;
    if (doF || doH) {
      const float* vv = doF ? &part[w][0] : &part[w][32];
      for (int kk = 0; kk < 32; ++kk) {
        c += vv[kk] * cosf(PI_F * j * (kk + 0.5f) / 32.0f);
      }
      c *= (j == 0) ? (1.0f / 32.0f) : (2.0f / 32.0f);
    }
    __syncthreads();
    if (doF) part[w][j] = c;
    if (doH) part[w][32 + j] = c;
    __syncthreads();
    // Chebyshev -> monomial (u = S/ADOM), fold ADOM^-k into coeff
    if (doF || doH) {
      const float* cc = doF ? &part[w][0] : &part[w][32];
      float m = 0.0f;
      #pragma unroll
      for (int jj = 0; jj < 12; ++jj) m += cc[jj] * TCmat[jj][j];
      m *= powf(1.0f / ADOM, (float)j);
      coefs[w * 2 * NDEG + (doF ? 0 : NDEG) + j] = m;
    }
  }
}

// ---------------- Kernel 2: edges_prob via bf16 MFMA + Horner ----------------
__device__ __forceinline__ bf16x8 frag_read(const ushort* buf, int prow, int dbyte) {
  int off = prow * 128 + (dbyte ^ ((prow & 7) << 4));
  return *(const bf16x8*)((const char*)buf + off);
}

__global__ __launch_bounds__(256, 4) void edge_kernel(
    const u64* __restrict__ ME, const u64* __restrict__ MT,
    const float* __restrict__ persona, const int* __restrict__ timesP,
    const float* __restrict__ coefs, const ushort* __restrict__ Fnb,
    float* __restrict__ out)
{
  __shared__ ushort Ab[64 * 64];
  __shared__ ushort Bb[64 * 64];
  __shared__ u64 meL[64][4], mtL[64][4];

  int t = threadIdx.x;
  int w = t >> 6, l = t & 63;
  int wr = w >> 1, wc = w & 1;
  int lr = l >> 4, lc = l & 15;
  int row0 = blockIdx.y * 64;
  int col0 = blockIdx.x * 64;
  int times = timesP[0];

  // stage mask words: 512 u64, each thread loads 2
  {
    int rr = t >> 2, jj = t & 3;
    int cb4 = (col0 >> 8) * 4;
    meL[rr][jj] = ME[(size_t)(row0 + rr) * 32 + cb4 + jj];
    mtL[rr][jj] = MT[(size_t)(row0 + rr) * 32 + cb4 + jj];
  }
  __syncthreads();

  // ---- masks for my 16 elements (MFMA C/D layout) ----
  uint mem = 0, mtm = 0;
  {
    int j = lc & 3;
    int s0 = ((col0 & 255) >> 2) + wc * 8 + (lc >> 2);
    #pragma unroll
    for (int mt_ = 0; mt_ < 2; ++mt_) {
      #pragma unroll
      for (int jr = 0; jr < 4; ++jr) {
        int rowl = wr * 32 + mt_ * 16 + lr * 4 + jr;
        u64 mew = meL[rowl][j], mtw = mtL[rowl][j];
        #pragma unroll
        for (int nt_ = 0; nt_ < 2; ++nt_) {
          int bp = s0 + nt_ * 4;
          int b = (mt_ * 2 + nt_) * 4 + jr;
          mem |= (uint)((mew >> bp) & 1ull) << b;
          mtm |= (uint)((mtw >> bp) & 1ull) << b;
        }
      }
    }
  }

  // ---- persona for my 2 column tiles, all 4 components ----
  float pc[KP][2];
  #pragma unroll
  for (int i = 0; i < KP; ++i) {
    #pragma unroll
    for (int nt_ = 0; nt_ < 2; ++nt_) {
      int col = col0 + wc * 32 + nt_ * 16 + lc;
      pc[i][nt_] = persona[((size_t)times * N + col) * KP + i];
    }
  }

  f32x4 acc[2][2] = {};

  #pragma unroll
  for (int i = 0; i < KP; ++i) {
    __syncthreads();
    // ---- stage Fn panels (bf16, swizzled) ----
    {
      int r = t >> 2, q = t & 3;
      uint sw = (uint)((r & 7) << 4);
      const char* srcA = (const char*)(Fnb + ((size_t)i * N + row0 + r) * D);
      uint4v a0 = *(const uint4v*)(srcA + q * 32);
      uint4v a1 = *(const uint4v*)(srcA + q * 32 + 16);
      char* dstA = (char*)Ab + r * 128;
      *(uint4v*)(dstA + ((q * 32) ^ sw)) = a0;
      *(uint4v*)(dstA + ((q * 32 + 16) ^ sw)) = a1;
      const char* srcB = (const char*)(Fnb + ((size_t)i * N + col0 + r) * D);
      uint4v b0 = *(const uint4v*)(srcB + q * 32);
      uint4v b1 = *(const uint4v*)(srcB + q * 32 + 16);
      char* dstB = (char*)Bb + r * 128;
      *(uint4v*)(dstB + ((q * 32) ^ sw)) = b0;
      *(uint4v*)(dstB + ((q * 32 + 16) ^ sw)) = b1;
    }
    __syncthreads();

    // ---- S quadrant via MFMA ----
    f32x4 S[2][2] = {};
    #pragma unroll
    for (int ks = 0; ks < 2; ++ks) {
      int dbyte = ks * 64 + lr * 16;
      bf16x8 a0 = frag_read(Ab, wr * 32 + lc, dbyte);
      bf16x8 a1 = frag_read(Ab, wr * 32 + 16 + lc, dbyte);
      bf16x8 b0 = frag_read(Bb, wc * 32 + lc, dbyte);
      bf16x8 b1 = frag_read(Bb, wc * 32 + 16 + lc, dbyte);
      S[0][0] = __builtin_amdgcn_mfma_f32_16x16x32_bf16(a0, b0, S[0][0], 0, 0, 0);
      S[0][1] = __builtin_amdgcn_mfma_f32_16x16x32_bf16(a0, b1, S[0][1], 0, 0, 0);
      S[1][0] = __builtin_amdgcn_mfma_f32_16x16x32_bf16(a1, b0, S[1][0], 0, 0, 0);
      S[1][1] = __builtin_amdgcn_mfma_f32_16x16x32_bf16(a1, b1, S[1][1], 0, 0, 0);
    }

    // ---- nonlinearity: Horner polys (no transcendentals) ----
    float cF[NDEG], cH[NDEG];
    #pragma unroll
    for (int jj = 0; jj < NDEG; ++jj) {
      cF[jj] = coefs[i * 2 * NDEG + jj];
      cH[jj] = coefs[i * 2 * NDEG + NDEG + jj];
    }
    #pragma unroll
    for (int mt_ = 0; mt_ < 2; ++mt_) {
      #pragma unroll
      for (int nt_ = 0; nt_ < 2; ++nt_) {
        float pcv = pc[i][nt_];
        int bb = (mt_ * 2 + nt_) * 4;
        #pragma unroll
        for (int j = 0; j < 4; ++j) {
          float sv = fminf(fmaxf(S[mt_][nt_][j], -ADOM), ADOM);
          float v = cF[NDEG - 1];
          #pragma unroll
          for (int jj = NDEG - 2; jj >= 0; --jj) v = fmaf(v, sv, cF[jj]);
          if ((mem >> (bb + j)) & 1) {
            float vh = cH[NDEG - 1];
            #pragma unroll
            for (int jj = NDEG - 2; jj >= 0; --jj) vh = fmaf(vh, sv, cH[jj]);
            v = vh;
          }
          acc[mt_][nt_][j] += ((mtm >> (bb + j)) & 1) ? v * pcv : 0.0f;
        }
      }
    }
  }

  // ---- store ----
  #pragma unroll
  for (int mt_ = 0; mt_ < 2; ++mt_) {
    #pragma unroll
    for (int nt_ = 0; nt_ < 2; ++nt_) {
      #pragma unroll
      for (int j = 0; j < 4; ++j) {
        int row = row0 + wr * 32 + mt_ * 16 + lr * 4 + j;
        int col = col0 + wc * 32 + nt_ * 16 + lc;
        out[(size_t)row * N + col] = acc[mt_][nt_][j];
      }
    }
  }
}

extern "C" void kernel_launch(void* const* d_in, const int* in_sizes, int n_in,
                              void* d_out, int out_size, void* d_ws, size_t ws_size,
                              hipStream_t stream) {
  const float* attributes = (const float*)d_in[0];
  const float* edges      = (const float*)d_in[1];
  const float* two_hop    = (const float*)d_in[2];
  const float* persona    = (const float*)d_in[3];
  const float* Tp         = (const float*)d_in[4];
  const float* ep         = (const float*)d_in[5];
  const float* rp         = (const float*)d_in[6];
  const float* Wp         = (const float*)d_in[7];
  const int*   timesP     = (const int*)d_in[8];
  float* out = (float*)d_out;

  // ws: Fnb [KP][N][D] bf16 (1MB), ME (512KB), MT (512KB), coefs (96 f32)
  ushort* Fnb = (ushort*)d_ws;
  u64* ME = (u64*)((char*)d_ws + (size_t)KP * N * D * 2);
  u64* MT = ME + (size_t)N * 32;
  float* coefs = (float*)(MT + (size_t)N * 32);

  row_kernel<<<N, 256, 0, stream>>>(attributes, edges, two_hop, persona,
                                    timesP, rp, Wp, Tp, ep, Fnb, ME, MT,
                                    coefs, out);
  edge_kernel<<<dim3(N / 64, N / 64), 256, 0, stream>>>(
      ME, MT, persona, timesP, coefs, Fnb, out);
}

// Round 7
// 28.759 us; speedup vs baseline: 1.2425x; 1.2425x over previous
//
#include <hip/hip_runtime.h>
#include <math.h>

#define N 2048
#define D 64
#define KP 4
#define NLUT 128
#define ADOM 1.02f

typedef unsigned int uint;
typedef unsigned short ushort;
typedef unsigned long long u64;
typedef __attribute__((ext_vector_type(8))) short bf16x8;
typedef __attribute__((ext_vector_type(4))) float f32x4;
typedef __attribute__((ext_vector_type(4))) uint uint4v;

// float -> bf16 round-to-nearest-even
__device__ __forceinline__ ushort f2bf(float f) {
  uint u = __builtin_bit_cast(uint, f);
  u += 0x7FFFu + ((u >> 16) & 1u);
  return (ushort)(u >> 16);
}

// Mask layout: per row, 8 chunks of 256 cols; each chunk = 4 u64 words.
// Bit l of word j  <->  col = chunk*256 + 4*l + j.

// ---------------- Kernel 1: masks + EA + feat + Fn_bf16 + attr_prob -------
// Block 0 additionally tabulates f_i(S)=tanh(e_i*exp(S/T_i)) and
// h_i(S)=f_i(S)*tanh(e_i*exp((1-S)/T_i)) at 129 nodes on [-ADOM, ADOM].
__global__ __launch_bounds__(256) void row_kernel(
    const float* __restrict__ attr, const float* __restrict__ edges,
    const float* __restrict__ two_hop, const float* __restrict__ persona,
    const int* __restrict__ timesP, const float* __restrict__ rp,
    const float* __restrict__ Wp, const float* __restrict__ Tp,
    const float* __restrict__ ep, ushort* __restrict__ Fnb,
    u64* __restrict__ ME, u64* __restrict__ MT, float* __restrict__ tbl,
    float* __restrict__ out)
{
  __shared__ float part[4][64];

  int t = threadIdx.x;
  int w = t >> 6, l = t & 63;
  int row = blockIdx.x;

  const float4* erow4 = reinterpret_cast<const float4*>(edges + (size_t)row * N);
  const float4* trow4 = reinterpret_cast<const float4*>(two_hop + (size_t)row * N);

  u64 mw[2][4];
  #pragma unroll
  for (int cc = 0; cc < 2; ++cc) {
    int chunk = 2 * w + cc;
    float4 ev = erow4[chunk * 64 + l];
    float4 tv = trow4[chunk * 64 + l];
    int colb = chunk * 256 + 4 * l;
    float evs[4] = {ev.x, ev.y, ev.z, ev.w};
    float tvs[4] = {tv.x, tv.y, tv.z, tv.w};
    #pragma unroll
    for (int jj = 0; jj < 4; ++jj) {
      bool eb = evs[jj] != 0.0f;
      u64 meb = __ballot(eb);
      u64 mtb = __ballot((eb || tvs[jj] != 0.0f) && (colb + jj != row));
      mw[cc][jj] = meb;
      if (l == jj) {
        ME[(size_t)row * 32 + chunk * 4 + jj] = meb;
        MT[(size_t)row * 32 + chunk * 4 + jj] = mtb;
      }
    }
  }

  // EA gather: lane l = dimension d
  float acc = 0.0f;
  #pragma unroll
  for (int cc = 0; cc < 2; ++cc) {
    #pragma unroll
    for (int jj = 0; jj < 4; ++jj) {
      u64 word = mw[cc][jj];
      int base = (2 * w + cc) * 256 + jj;
      while (word) {
        int b = __builtin_ctzll(word);
        word &= word - 1;
        acc += attr[(size_t)(base + 4 * b) * D + l];
      }
    }
  }
  part[w][l] = acc;
  __syncthreads();
  float ea = part[0][l] + part[1][l] + part[2][l] + part[3][l];
  __syncthreads();   // before part reuse

  // wave w handles persona component i = w
  float a = attr[(size_t)row * D + l];
  float ri = rp[w], Wi = Wp[w];
  float nf = ri * a + ea * Wi * (1.0f - ri);
  float ss = nf * nf;
  #pragma unroll
  for (int off = 32; off; off >>= 1) ss += __shfl_xor(ss, off);
  float inv = rsqrtf(ss);
  Fnb[((size_t)w * N + row) * D + l] = f2bf(nf * inv);

  int times = timesP[0];
  float p = persona[((size_t)times * N + row) * KP + w];
  float sig = 1.0f / (1.0f + __expf(-nf));
  part[w][l] = p * sig;
  __syncthreads();
  if (w == 0) {
    out[(size_t)N * N + (size_t)row * D + l] =
        part[0][l] + part[1][l] + part[2][l] + part[3][l];
  }

  // ---- block 0: build LUT nodes (519 evals spread over 256 threads) ----
  if (row == 0) {
    for (int idx = t; idx < KP * (NLUT + 1); idx += 256) {
      int i = idx / (NLUT + 1), k = idx - i * (NLUT + 1);
      float s = -ADOM + (2.0f * ADOM / NLUT) * k;
      float invT = 1.0f / Tp[i];
      float ei = ep[i];
      float fv = tanhf(ei * expf(s * invT));
      float hv = fv * tanhf(ei * expf((1.0f - s) * invT));
      tbl[(i * (NLUT + 1) + k) * 2 + 0] = fv;
      tbl[(i * (NLUT + 1) + k) * 2 + 1] = hv;
    }
  }
}

// ---------------- Kernel 2: edges_prob via bf16 MFMA + LDS LUT ------------
__device__ __forceinline__ bf16x8 frag_read(const ushort* buf, int prow, int dbyte) {
  int off = prow * 128 + (dbyte ^ ((prow & 7) << 4));
  return *(const bf16x8*)((const char*)buf + off);
}

__global__ __launch_bounds__(256, 4) void edge_kernel(
    const u64* __restrict__ ME, const u64* __restrict__ MT,
    const float* __restrict__ persona, const int* __restrict__ timesP,
    const float* __restrict__ tbl, const ushort* __restrict__ Fnb,
    float* __restrict__ out)
{
  __shared__ ushort Ab[64 * 64];
  __shared__ ushort Bb[64 * 64];
  __shared__ u64 meL[64][4], mtL[64][4];
  __shared__ float4 lutL[KP][NLUT];   // (f_k, h_k, f_{k+1}, h_{k+1})

  int t = threadIdx.x;
  int w = t >> 6, l = t & 63;
  int wr = w >> 1, wc = w & 1;
  int lr = l >> 4, lc = l & 15;
  int row0 = blockIdx.y * 64;
  int col0 = blockIdx.x * 64;
  int times = timesP[0];

  // stage mask words (512 u64) + LUT (512 float4)
  {
    int rr = t >> 2, jj = t & 3;
    int cb4 = (col0 >> 8) * 4;
    meL[rr][jj] = ME[(size_t)(row0 + rr) * 32 + cb4 + jj];
    mtL[rr][jj] = MT[(size_t)(row0 + rr) * 32 + cb4 + jj];
    #pragma unroll
    for (int pass = 0; pass < 2; ++pass) {
      int idx = t + pass * 256;
      int i = idx >> 7, k = idx & (NLUT - 1);
      const float* src = tbl + (i * (NLUT + 1) + k) * 2;
      float2 a = *(const float2*)(src);
      float2 b = *(const float2*)(src + 2);
      lutL[i][k] = make_float4(a.x, a.y, b.x, b.y);
    }
  }
  __syncthreads();

  // ---- masks for my 16 elements (MFMA C/D layout) ----
  uint mem = 0, mtm = 0;
  {
    int j = lc & 3;
    int s0 = ((col0 & 255) >> 2) + wc * 8 + (lc >> 2);
    #pragma unroll
    for (int mt_ = 0; mt_ < 2; ++mt_) {
      #pragma unroll
      for (int jr = 0; jr < 4; ++jr) {
        int rowl = wr * 32 + mt_ * 16 + lr * 4 + jr;
        u64 mew = meL[rowl][j], mtw = mtL[rowl][j];
        #pragma unroll
        for (int nt_ = 0; nt_ < 2; ++nt_) {
          int bp = s0 + nt_ * 4;
          int b = (mt_ * 2 + nt_) * 4 + jr;
          mem |= (uint)((mew >> bp) & 1ull) << b;
          mtm |= (uint)((mtw >> bp) & 1ull) << b;
        }
      }
    }
  }

  // ---- persona for my 2 column tiles, all 4 components ----
  float pc[KP][2];
  #pragma unroll
  for (int i = 0; i < KP; ++i) {
    #pragma unroll
    for (int nt_ = 0; nt_ < 2; ++nt_) {
      int col = col0 + wc * 32 + nt_ * 16 + lc;
      pc[i][nt_] = persona[((size_t)times * N + col) * KP + i];
    }
  }

  f32x4 acc[2][2] = {};

  const float SCALE = (float)NLUT / (2.0f * ADOM);
  const float OFF   = ADOM * SCALE;          // = NLUT/2
  const float UMAX  = (float)NLUT - 0.001f;

  #pragma unroll
  for (int i = 0; i < KP; ++i) {
    __syncthreads();
    // ---- stage Fn panels (bf16, swizzled) ----
    {
      int r = t >> 2, q = t & 3;
      uint sw = (uint)((r & 7) << 4);
      const char* srcA = (const char*)(Fnb + ((size_t)i * N + row0 + r) * D);
      uint4v a0 = *(const uint4v*)(srcA + q * 32);
      uint4v a1 = *(const uint4v*)(srcA + q * 32 + 16);
      char* dstA = (char*)Ab + r * 128;
      *(uint4v*)(dstA + ((q * 32) ^ sw)) = a0;
      *(uint4v*)(dstA + ((q * 32 + 16) ^ sw)) = a1;
      const char* srcB = (const char*)(Fnb + ((size_t)i * N + col0 + r) * D);
      uint4v b0 = *(const uint4v*)(srcB + q * 32);
      uint4v b1 = *(const uint4v*)(srcB + q * 32 + 16);
      char* dstB = (char*)Bb + r * 128;
      *(uint4v*)(dstB + ((q * 32) ^ sw)) = b0;
      *(uint4v*)(dstB + ((q * 32 + 16) ^ sw)) = b1;
    }
    __syncthreads();

    // ---- S quadrant via MFMA ----
    f32x4 S[2][2] = {};
    #pragma unroll
    for (int ks = 0; ks < 2; ++ks) {
      int dbyte = ks * 64 + lr * 16;
      bf16x8 a0 = frag_read(Ab, wr * 32 + lc, dbyte);
      bf16x8 a1 = frag_read(Ab, wr * 32 + 16 + lc, dbyte);
      bf16x8 b0 = frag_read(Bb, wc * 32 + lc, dbyte);
      bf16x8 b1 = frag_read(Bb, wc * 32 + 16 + lc, dbyte);
      S[0][0] = __builtin_amdgcn_mfma_f32_16x16x32_bf16(a0, b0, S[0][0], 0, 0, 0);
      S[0][1] = __builtin_amdgcn_mfma_f32_16x16x32_bf16(a0, b1, S[0][1], 0, 0, 0);
      S[1][0] = __builtin_amdgcn_mfma_f32_16x16x32_bf16(a1, b0, S[1][0], 0, 0, 0);
      S[1][1] = __builtin_amdgcn_mfma_f32_16x16x32_bf16(a1, b1, S[1][1], 0, 0, 0);
    }

    // ---- nonlinearity: branchless LUT + lerp ----
    #pragma unroll
    for (int mt_ = 0; mt_ < 2; ++mt_) {
      #pragma unroll
      for (int nt_ = 0; nt_ < 2; ++nt_) {
        float pcv = pc[i][nt_];
        int bb = (mt_ * 2 + nt_) * 4;
        #pragma unroll
        for (int j = 0; j < 4; ++j) {
          float u = fmaf(S[mt_][nt_][j], SCALE, OFF);
          u = fminf(fmaxf(u, 0.0f), UMAX);
          float kf = floorf(u);
          float tt = u - kf;
          float4 v4 = lutL[i][(int)kf];
          float fv = fmaf(tt, v4.z - v4.x, v4.x);
          float hv = fmaf(tt, v4.w - v4.y, v4.y);
          float v = ((mem >> (bb + j)) & 1) ? hv : fv;
          acc[mt_][nt_][j] += ((mtm >> (bb + j)) & 1) ? v * pcv : 0.0f;
        }
      }
    }
  }

  // ---- store ----
  #pragma unroll
  for (int mt_ = 0; mt_ < 2; ++mt_) {
    #pragma unroll
    for (int nt_ = 0; nt_ < 2; ++nt_) {
      #pragma unroll
      for (int j = 0; j < 4; ++j) {
        int row = row0 + wr * 32 + mt_ * 16 + lr * 4 + j;
        int col = col0 + wc * 32 + nt_ * 16 + lc;
        out[(size_t)row * N + col] = acc[mt_][nt_][j];
      }
    }
  }
}

extern "C" void kernel_launch(void* const* d_in, const int* in_sizes, int n_in,
                              void* d_out, int out_size, void* d_ws, size_t ws_size,
                              hipStream_t stream) {
  const float* attributes = (const float*)d_in[0];
  const float* edges      = (const float*)d_in[1];
  const float* two_hop    = (const float*)d_in[2];
  const float* persona    = (const float*)d_in[3];
  const float* Tp         = (const float*)d_in[4];
  const float* ep         = (const float*)d_in[5];
  const float* rp         = (const float*)d_in[6];
  const float* Wp         = (const float*)d_in[7];
  const int*   timesP     = (const int*)d_in[8];
  float* out = (float*)d_out;

  // ws: Fnb [KP][N][D] bf16 (1MB), ME (512KB), MT (512KB), tbl (1032 f32)
  ushort* Fnb = (ushort*)d_ws;
  u64* ME = (u64*)((char*)d_ws + (size_t)KP * N * D * 2);
  u64* MT = ME + (size_t)N * 32;
  float* tbl = (float*)(MT + (size_t)N * 32);

  row_kernel<<<N, 256, 0, stream>>>(attributes, edges, two_hop, persona,
                                    timesP, rp, Wp, Tp, ep, Fnb, ME, MT,
                                    tbl, out);
  edge_kernel<<<dim3(N / 64, N / 64), 256, 0, stream>>>(
      ME, MT, persona, timesP, tbl, Fnb, out);
}

// Round 8
// 27.655 us; speedup vs baseline: 1.2921x; 1.0399x over previous
//
#include <hip/hip_runtime.h>
#include <math.h>

#define N 2048
#define D 64
#define KP 4
#define NLUT 128
#define ADOM 1.02f

typedef unsigned int uint;
typedef unsigned short ushort;
typedef unsigned long long u64;
typedef __attribute__((ext_vector_type(8))) short bf16x8;
typedef __attribute__((ext_vector_type(4))) float f32x4;
typedef __attribute__((ext_vector_type(4))) uint uint4v;

// float -> bf16 round-to-nearest-even
__device__ __forceinline__ ushort f2bf(float f) {
  uint u = __builtin_bit_cast(uint, f);
  u += 0x7FFFu + ((u >> 16) & 1u);
  return (ushort)(u >> 16);
}

// Mask layout: per row, 8 chunks of 256 cols; each chunk = 4 u64 words.
// Bit l of word j  <->  col = chunk*256 + 4*l + j.

// ---------------- Kernel 1: masks + EA + feat + Fn_bf16 + attr_prob -------
// Block 0 additionally tabulates f_i(S)=tanh(e_i*exp(S/T_i)) and
// h_i(S)=f_i(S)*tanh(e_i*exp((1-S)/T_i)) at 129 nodes on [-ADOM, ADOM].
__global__ __launch_bounds__(256) void row_kernel(
    const float* __restrict__ attr, const float* __restrict__ edges,
    const float* __restrict__ two_hop, const float* __restrict__ persona,
    const int* __restrict__ timesP, const float* __restrict__ rp,
    const float* __restrict__ Wp, const float* __restrict__ Tp,
    const float* __restrict__ ep, ushort* __restrict__ Fnb,
    u64* __restrict__ ME, u64* __restrict__ MT, float* __restrict__ tbl,
    float* __restrict__ out)
{
  __shared__ float part[4][64];

  int t = threadIdx.x;
  int w = t >> 6, l = t & 63;
  int row = blockIdx.x;

  const float4* erow4 = reinterpret_cast<const float4*>(edges + (size_t)row * N);
  const float4* trow4 = reinterpret_cast<const float4*>(two_hop + (size_t)row * N);

  u64 mw[2][4];
  #pragma unroll
  for (int cc = 0; cc < 2; ++cc) {
    int chunk = 2 * w + cc;
    float4 ev = erow4[chunk * 64 + l];
    float4 tv = trow4[chunk * 64 + l];
    int colb = chunk * 256 + 4 * l;
    float evs[4] = {ev.x, ev.y, ev.z, ev.w};
    float tvs[4] = {tv.x, tv.y, tv.z, tv.w};
    #pragma unroll
    for (int jj = 0; jj < 4; ++jj) {
      bool eb = evs[jj] != 0.0f;
      u64 meb = __ballot(eb);
      u64 mtb = __ballot((eb || tvs[jj] != 0.0f) && (colb + jj != row));
      mw[cc][jj] = meb;
      if (l == jj) {
        ME[(size_t)row * 32 + chunk * 4 + jj] = meb;
        MT[(size_t)row * 32 + chunk * 4 + jj] = mtb;
      }
    }
  }

  // EA gather: lane l = dimension d
  float acc = 0.0f;
  #pragma unroll
  for (int cc = 0; cc < 2; ++cc) {
    #pragma unroll
    for (int jj = 0; jj < 4; ++jj) {
      u64 word = mw[cc][jj];
      int base = (2 * w + cc) * 256 + jj;
      while (word) {
        int b = __builtin_ctzll(word);
        word &= word - 1;
        acc += attr[(size_t)(base + 4 * b) * D + l];
      }
    }
  }
  part[w][l] = acc;
  __syncthreads();
  float ea = part[0][l] + part[1][l] + part[2][l] + part[3][l];
  __syncthreads();   // before part reuse

  // wave w handles persona component i = w
  float a = attr[(size_t)row * D + l];
  float ri = rp[w], Wi = Wp[w];
  float nf = ri * a + ea * Wi * (1.0f - ri);
  float ss = nf * nf;
  #pragma unroll
  for (int off = 32; off; off >>= 1) ss += __shfl_xor(ss, off);
  float inv = rsqrtf(ss);
  Fnb[((size_t)w * N + row) * D + l] = f2bf(nf * inv);

  int times = timesP[0];
  float p = persona[((size_t)times * N + row) * KP + w];
  float sig = 1.0f / (1.0f + __expf(-nf));
  part[w][l] = p * sig;
  __syncthreads();
  if (w == 0) {
    out[(size_t)N * N + (size_t)row * D + l] =
        part[0][l] + part[1][l] + part[2][l] + part[3][l];
  }

  // ---- block 0: build LUT nodes (516 evals spread over 256 threads) ----
  if (row == 0) {
    for (int idx = t; idx < KP * (NLUT + 1); idx += 256) {
      int i = idx / (NLUT + 1), k = idx - i * (NLUT + 1);
      float s = -ADOM + (2.0f * ADOM / NLUT) * k;
      float invT = 1.0f / Tp[i];
      float ei = ep[i];
      float fv = tanhf(ei * expf(s * invT));
      float hv = fv * tanhf(ei * expf((1.0f - s) * invT));
      tbl[(i * (NLUT + 1) + k) * 2 + 0] = fv;
      tbl[(i * (NLUT + 1) + k) * 2 + 1] = hv;
    }
  }
}

// ---------------- Kernel 2: edges_prob via bf16 MFMA + split LDS LUT ------
__device__ __forceinline__ bf16x8 frag_read(const ushort* buf, int prow, int dbyte) {
  int off = prow * 128 + (dbyte ^ ((prow & 7) << 4));
  return *(const bf16x8*)((const char*)buf + off);
}

__global__ __launch_bounds__(256, 4) void edge_kernel(
    const u64* __restrict__ ME, const u64* __restrict__ MT,
    const float* __restrict__ persona, const int* __restrict__ timesP,
    const float* __restrict__ tbl, const ushort* __restrict__ Fnb,
    float* __restrict__ out)
{
  __shared__ ushort Ab[64 * 64];
  __shared__ ushort Bb[64 * 64];
  __shared__ u64 meL[64][4], mtL[64][4];
  // lut2[sel][i][k] = (g_k, g_{k+1}); sel 0 = f (two-hop), 1 = h (common)
  __shared__ float2 lut2[2 * KP * NLUT];

  int t = threadIdx.x;
  int w = t >> 6, l = t & 63;
  int wr = w >> 1, wc = w & 1;
  int lr = l >> 4, lc = l & 15;
  int row0 = blockIdx.y * 64;
  int col0 = blockIdx.x * 64;
  int times = timesP[0];

  // stage mask words (512 u64) + split LUT (1024 float2)
  {
    int rr = t >> 2, jj = t & 3;
    int cb4 = (col0 >> 8) * 4;
    meL[rr][jj] = ME[(size_t)(row0 + rr) * 32 + cb4 + jj];
    mtL[rr][jj] = MT[(size_t)(row0 + rr) * 32 + cb4 + jj];
    #pragma unroll
    for (int pass = 0; pass < 2; ++pass) {
      int idx = t + pass * 256;         // 0..511 over [i][k]
      int i = idx >> 7, k = idx & (NLUT - 1);
      const float* src = tbl + (i * (NLUT + 1) + k) * 2;
      float2 a = *(const float2*)(src);       // (f_k, h_k)
      float2 b = *(const float2*)(src + 2);   // (f_{k+1}, h_{k+1})
      lut2[idx] = make_float2(a.x, b.x);                 // f pair
      lut2[KP * NLUT + idx] = make_float2(a.y, b.y);     // h pair
    }
  }
  __syncthreads();

  // ---- masks for my 16 elements (MFMA C/D layout) ----
  uint mem = 0, mtm = 0;
  {
    int j = lc & 3;
    int s0 = ((col0 & 255) >> 2) + wc * 8 + (lc >> 2);
    #pragma unroll
    for (int mt_ = 0; mt_ < 2; ++mt_) {
      #pragma unroll
      for (int jr = 0; jr < 4; ++jr) {
        int rowl = wr * 32 + mt_ * 16 + lr * 4 + jr;
        u64 mew = meL[rowl][j], mtw = mtL[rowl][j];
        #pragma unroll
        for (int nt_ = 0; nt_ < 2; ++nt_) {
          int bp = s0 + nt_ * 4;
          int b = (mt_ * 2 + nt_) * 4 + jr;
          mem |= (uint)((mew >> bp) & 1ull) << b;
          mtm |= (uint)((mtw >> bp) & 1ull) << b;
        }
      }
    }
  }

  // ---- persona for my 2 column tiles, all 4 components ----
  float pc[KP][2];
  #pragma unroll
  for (int i = 0; i < KP; ++i) {
    #pragma unroll
    for (int nt_ = 0; nt_ < 2; ++nt_) {
      int col = col0 + wc * 32 + nt_ * 16 + lc;
      pc[i][nt_] = persona[((size_t)times * N + col) * KP + i];
    }
  }

  f32x4 acc[2][2] = {};

  const float SCALE = (float)NLUT / (2.0f * ADOM);
  const float OFF   = ADOM * SCALE;          // = NLUT/2
  const float UMAX  = (float)NLUT - 0.001f;

  #pragma unroll
  for (int i = 0; i < KP; ++i) {
    __syncthreads();
    // ---- stage Fn panels (bf16, swizzled) ----
    {
      int r = t >> 2, q = t & 3;
      uint sw = (uint)((r & 7) << 4);
      const char* srcA = (const char*)(Fnb + ((size_t)i * N + row0 + r) * D);
      uint4v a0 = *(const uint4v*)(srcA + q * 32);
      uint4v a1 = *(const uint4v*)(srcA + q * 32 + 16);
      char* dstA = (char*)Ab + r * 128;
      *(uint4v*)(dstA + ((q * 32) ^ sw)) = a0;
      *(uint4v*)(dstA + ((q * 32 + 16) ^ sw)) = a1;
      const char* srcB = (const char*)(Fnb + ((size_t)i * N + col0 + r) * D);
      uint4v b0 = *(const uint4v*)(srcB + q * 32);
      uint4v b1 = *(const uint4v*)(srcB + q * 32 + 16);
      char* dstB = (char*)Bb + r * 128;
      *(uint4v*)(dstB + ((q * 32) ^ sw)) = b0;
      *(uint4v*)(dstB + ((q * 32 + 16) ^ sw)) = b1;
    }
    __syncthreads();

    // ---- S quadrant via MFMA ----
    f32x4 S[2][2] = {};
    #pragma unroll
    for (int ks = 0; ks < 2; ++ks) {
      int dbyte = ks * 64 + lr * 16;
      bf16x8 a0 = frag_read(Ab, wr * 32 + lc, dbyte);
      bf16x8 a1 = frag_read(Ab, wr * 32 + 16 + lc, dbyte);
      bf16x8 b0 = frag_read(Bb, wc * 32 + lc, dbyte);
      bf16x8 b1 = frag_read(Bb, wc * 32 + 16 + lc, dbyte);
      S[0][0] = __builtin_amdgcn_mfma_f32_16x16x32_bf16(a0, b0, S[0][0], 0, 0, 0);
      S[0][1] = __builtin_amdgcn_mfma_f32_16x16x32_bf16(a0, b1, S[0][1], 0, 0, 0);
      S[1][0] = __builtin_amdgcn_mfma_f32_16x16x32_bf16(a1, b0, S[1][0], 0, 0, 0);
      S[1][1] = __builtin_amdgcn_mfma_f32_16x16x32_bf16(a1, b1, S[1][1], 0, 0, 0);
    }

    // ---- nonlinearity: address-selected table, single lerp ----
    int ibase = i * NLUT;
    #pragma unroll
    for (int mt_ = 0; mt_ < 2; ++mt_) {
      #pragma unroll
      for (int nt_ = 0; nt_ < 2; ++nt_) {
        float pcv = pc[i][nt_];
        int bb = (mt_ * 2 + nt_) * 4;
        #pragma unroll
        for (int j = 0; j < 4; ++j) {
          float u = fmaf(S[mt_][nt_][j], SCALE, OFF);
          u = fminf(fmaxf(u, 0.0f), UMAX);
          float kf = floorf(u);
          float tt = u - kf;
          int idx = ibase + (int)kf + (((mem >> (bb + j)) & 1) ? KP * NLUT : 0);
          float2 v2 = lut2[idx];
          float v = fmaf(tt, v2.y - v2.x, v2.x);
          float pcz = ((mtm >> (bb + j)) & 1) ? pcv : 0.0f;
          acc[mt_][nt_][j] = fmaf(v, pcz, acc[mt_][nt_][j]);
        }
      }
    }
  }

  // ---- store ----
  #pragma unroll
  for (int mt_ = 0; mt_ < 2; ++mt_) {
    #pragma unroll
    for (int nt_ = 0; nt_ < 2; ++nt_) {
      #pragma unroll
      for (int j = 0; j < 4; ++j) {
        int row = row0 + wr * 32 + mt_ * 16 + lr * 4 + j;
        int col = col0 + wc * 32 + nt_ * 16 + lc;
        out[(size_t)row * N + col] = acc[mt_][nt_][j];
      }
    }
  }
}

extern "C" void kernel_launch(void* const* d_in, const int* in_sizes, int n_in,
                              void* d_out, int out_size, void* d_ws, size_t ws_size,
                              hipStream_t stream) {
  const float* attributes = (const float*)d_in[0];
  const float* edges      = (const float*)d_in[1];
  const float* two_hop    = (const float*)d_in[2];
  const float* persona    = (const float*)d_in[3];
  const float* Tp         = (const float*)d_in[4];
  const float* ep         = (const float*)d_in[5];
  const float* rp         = (const float*)d_in[6];
  const float* Wp         = (const float*)d_in[7];
  const int*   timesP     = (const int*)d_in[8];
  float* out = (float*)d_out;

  // ws: Fnb [KP][N][D] bf16 (1MB), ME (512KB), MT (512KB), tbl (1032 f32)
  ushort* Fnb = (ushort*)d_ws;
  u64* ME = (u64*)((char*)d_ws + (size_t)KP * N * D * 2);
  u64* MT = ME + (size_t)N * 32;
  float* tbl = (float*)(MT + (size_t)N * 32);

  row_kernel<<<N, 256, 0, stream>>>(attributes, edges, two_hop, persona,
                                    timesP, rp, Wp, Tp, ep, Fnb, ME, MT,
                                    tbl, out);
  edge_kernel<<<dim3(N / 64, N / 64), 256, 0, stream>>>(
      ME, MT, persona, timesP, tbl, Fnb, out);
}